// Round 17
// baseline (106.753 us; speedup 1.0000x reference)
//
#include <hip/hip_runtime.h>
#include <cstdint>

typedef __attribute__((ext_vector_type(8))) short short8;
typedef __attribute__((ext_vector_type(16))) float f32x16;
typedef __attribute__((ext_vector_type(4))) unsigned int uint4v;

__device__ inline uint32_t f2bf(float f) {
    union { float f; uint32_t u; } x; x.f = f;
    return (x.u + 0x7FFF + ((x.u >> 16) & 1)) >> 16;
}
__device__ inline uint32_t fbits(float f) {
    union { float f; uint32_t u; } x; x.f = f;
    return x.u;
}
__device__ inline float bflo(uint32_t u) {
    union { uint32_t u; float f; } x; x.u = u << 16; return x.f;
}
__device__ inline float bfhi(uint32_t u) {
    union { uint32_t u; float f; } x; x.u = u & 0xFFFF0000u; return x.f;
}

// Pass 1: X (bf16, MFMA-fragment order) + prep (bias-out init, AF build).
// X piece: tid = ((img*1024 + site)*4 + kidx)*64 + l ; elem e = src[b][site][co][o],
//          co = kidx*16+(l>>5)*8+e, o = l&31.
// AF: fragment-order kernel: AF[((tap*4+kidx)*2+c)*64 + l] = 8 bf16 A-elems
//          kk[(tap*64 + c*32 + (l&31))*64 + kidx*16 + (l>>5)*8 + e] (RNE).
__global__ __launch_bounds__(256) void k_xform(
    const float* __restrict__ wu, const float* __restrict__ wl,
    uint4v* __restrict__ X,
    const float* __restrict__ kk, uint4v* __restrict__ AF,
    const float* __restrict__ buI, const float* __restrict__ blI,
    float* __restrict__ buO, float* __restrict__ blO)
{
    int tid = blockIdx.x * 256 + threadIdx.x;   // 16384 blocks -> 4Mi pieces

    if (tid < 512 + 4608) {                     // folded prep
        if (tid < 256) buO[tid] = buI[tid];
        else if (tid < 512) blO[tid - 256] = blI[tid - 256];
        else {
            int a    = tid - 512;               // 4608 AF pieces
            int al   = a & 63;
            int c    = (a >> 6) & 1;
            int kidx = (a >> 7) & 3;
            int tap  = a >> 9;                  // 0..8
            const float* kp = kk + ((size_t)tap * 64 + c * 32 + (al & 31)) * 64
                                 + kidx * 16 + (al >> 5) * 8;
            uint4v w;
            #pragma unroll
            for (int pr = 0; pr < 4; pr++)
                w[pr] = f2bf(kp[2 * pr]) | (f2bf(kp[2 * pr + 1]) << 16);   // RNE
            AF[((tap * 4 + kidx) * 2 + c) * 64 + al] = w;
        }
    }

    int l    = tid & 63;
    int kidx = (tid >> 6) & 3;
    int site = (tid >> 8) & 1023;
    int img  = tid >> 18;                       // b*2 + UL
    int b    = img >> 1;
    const float* src = (img & 1) ? wl : wu;
    int o = l & 31, ch = l >> 5;

    const float* p = src + ((size_t)b * 65536 + (size_t)site * 64
                            + kidx * 16 + ch * 8) * 32 + o;
    uint4v w;
    #pragma unroll
    for (int pr = 0; pr < 4; pr++) {
        float g0 = p[(2 * pr) * 32];
        float g1 = p[(2 * pr + 1) * 32];
        w[pr] = __builtin_amdgcn_perm(fbits(g1), fbits(g0), 0x07060302u);
    }
    X[tid] = w;
}

// Pass 2: wave = 2 pixels x 1 ci-half (acc 32). B-batch split by kidx-PAIRS
// (8 frags = 32 VGPR in flight) -> ~105 unified regs -> launch_bounds(256,4):
// 4 waves/SIMD. Block = 4 waves (2 w-pairs x 2 ci-halves); UL serialized
// (XCD X working set = 1 image, L2-fit). All loads 1-KB-contiguous dwordx4.
__global__ __launch_bounds__(256, 4) void k_conv(
    const uint16_t* __restrict__ X, const uint16_t* __restrict__ AF,
    const float* __restrict__ bias,
    float* __restrict__ outU, float* __restrict__ outL,
    float* __restrict__ buO, float* __restrict__ blO)
{
    int tdx  = threadIdx.x;
    int l    = tdx & 63;
    int wid  = tdx >> 6;        // 0..3
    int o    = l & 31;
    int ch   = l >> 5;
    int c    = wid >> 1;        // ci-half owned by this wave
    int wsel = wid & 1;

    int bid = blockIdx.x;       // 2048
    int b   = bid & 7;          // XCD id
    int v   = bid >> 3;         // 0..255
    int h   = v & 31;
    int wq  = v >> 5;           // 0..7
    int w0  = wq * 4 + wsel * 2;   // wave's first pixel w

    bool sval[4] = { w0 != 0, true, true, w0 + 2 != 32 };
    const char* XB  = (const char*)X;
    const char* AFB = (const char*)AF;

    for (int UL = 0; UL < 2; UL++) {
        int img = b * 2 + UL;
        float* dst  = UL ? outL : outU;
        float* bdst = UL ? blO : buO;

        float bp = 0.f;
        f32x16 acc[2];              // [tw]
        acc[0] = (f32x16)0.f;
        acc[1] = (f32x16)0.f;

        for (int r = 0; r < 3; r++) {
            int hh = h + 1 - r;
            if ((unsigned)hh >= 32u) continue;      // wave-uniform

            // per-site base pointers for this row
            const char* ps[4];
            #pragma unroll
            for (int si = 0; si < 4; si++) {
                int ww  = w0 - 1 + si;
                int wwc = ((unsigned)ww < 32u) ? ww : 0;
                ps[si] = XB + ((size_t)(img * 1024 + hh * 32 + wwc)) * 4096
                            + (size_t)l * 16;
            }

            // ---- kidx-pair halves: load 8 frags (32 VGPR), consume 12 MFMA ----
            #pragma unroll
            for (int kp2 = 0; kp2 < 2; kp2++) {
                uint4v bw[4][2];
                #pragma unroll
                for (int si = 0; si < 4; si++) {
                    if (sval[si]) {
                        #pragma unroll
                        for (int kj = 0; kj < 2; kj++)
                            bw[si][kj] = *(const uint4v*)(ps[si] + (2 * kp2 + kj) * 1024);
                    } else {
                        bw[si][0] = (uint4v)0u;
                        bw[si][1] = (uint4v)0u;
                    }
                }

                #pragma unroll
                for (int kj = 0; kj < 2; kj++) {
                    int kidx = 2 * kp2 + kj;
                    short8 A[3];
                    #pragma unroll
                    for (int kw = 0; kw < 3; kw++)
                        A[kw] = *(const short8*)(AFB
                                + (size_t)((((r * 3 + kw) * 4 + kidx) * 2 + c) * 64 + l) * 16);

                    if (r == 1 && c == 0) {     // bias: own pixels (sites 1,2)
                        float4 b0 = *(const float4*)(bias + kidx * 16 + ch * 8);
                        float4 b1 = *(const float4*)(bias + kidx * 16 + ch * 8 + 4);
                        float bb[8] = {b0.x, b0.y, b0.z, b0.w, b1.x, b1.y, b1.z, b1.w};
                        #pragma unroll
                        for (int pr = 0; pr < 4; pr++) {
                            bp = fmaf(bflo(bw[1][kj][pr]), bb[2 * pr],
                                 fmaf(bfhi(bw[1][kj][pr]), bb[2 * pr + 1], bp));
                            bp = fmaf(bflo(bw[2][kj][pr]), bb[2 * pr],
                                 fmaf(bfhi(bw[2][kj][pr]), bb[2 * pr + 1], bp));
                        }
                    }

                    #pragma unroll
                    for (int si = 0; si < 4; si++) {
                        short8 Bf = __builtin_bit_cast(short8, bw[si][kj]);
                        #pragma unroll
                        for (int tw = 0; tw < 2; tw++) {
                            int kw = tw + 2 - si;       // compile-time under unroll
                            if (kw >= 0 && kw <= 2)
                                acc[tw] = __builtin_amdgcn_mfma_f32_32x32x16_bf16(
                                    A[kw], Bf, acc[tw], 0, 0, 0);
                        }
                    }
                }
            }
        }

        // bias reduction: lanes l, l^32 share o; c==0 wave only
        bp += __shfl_xor(bp, 32);
        if (l < 32 && c == 0) atomicAdd(&bdst[b * 32 + o], bp);

        // stores: col = o (coalesced), row = (reg&3)+8*(reg>>2)+4*(lane>>5)
        #pragma unroll
        for (int tw = 0; tw < 2; tw++) {
            int w = w0 + tw;
            float* base = dst + ((size_t)b * 65536 + (size_t)(h * 32 + w) * 64 + c * 32) * 32;
            #pragma unroll
            for (int reg = 0; reg < 16; reg++) {
                int row = (reg & 3) + 8 * (reg >> 2) + 4 * (l >> 5);
                base[row * 32 + o] = acc[tw][reg];
            }
        }
    }
}

extern "C" void kernel_launch(void* const* d_in, const int* in_sizes, int n_in,
                              void* d_out, int out_size, void* d_ws, size_t ws_size,
                              hipStream_t stream) {
    const float* wu   = (const float*)d_in[1];
    const float* buI  = (const float*)d_in[2];
    const float* wl   = (const float*)d_in[3];
    const float* blI  = (const float*)d_in[4];
    const float* kk   = (const float*)d_in[5];
    const float* bias = (const float*)d_in[6];

    float* out  = (float*)d_out;
    float* outU = out;
    float* buO  = out + 16777216;
    float* outL = out + 16777216 + 256;
    float* blO  = out + 2 * 16777216 + 256;

    uint4v* AF = (uint4v*)d_ws;                            // 73728 B
    const size_t XOFF = 131072;                            // 128 KiB aligned
    uint4v* X = (uint4v*)((char*)d_ws + XOFF);             // 64 MiB

    k_xform<<<16384, 256, 0, stream>>>(wu, wl, X, kk, AF, buI, blI, buO, blO);
    k_conv<<<2048, 256, 0, stream>>>((const uint16_t*)X, (const uint16_t*)AF, bias,
                                     outU, outL, buO, blO);
}

// Round 18
// 105.125 us; speedup vs baseline: 1.0155x; 1.0155x over previous
//
#include <hip/hip_runtime.h>
#include <cstdint>

typedef __attribute__((ext_vector_type(8))) short short8;
typedef __attribute__((ext_vector_type(16))) float f32x16;
typedef __attribute__((ext_vector_type(4))) unsigned int uint4v;

__device__ inline uint32_t f2bf(float f) {
    union { float f; uint32_t u; } x; x.f = f;
    return (x.u + 0x7FFF + ((x.u >> 16) & 1)) >> 16;
}
__device__ inline uint32_t fbits(float f) {
    union { float f; uint32_t u; } x; x.f = f;
    return x.u;
}
__device__ inline float bflo(uint32_t u) {
    union { uint32_t u; float f; } x; x.u = u << 16; return x.f;
}
__device__ inline float bfhi(uint32_t u) {
    union { uint32_t u; float f; } x; x.u = u & 0xFFFF0000u; return x.f;
}

// Pass 1: X (bf16, MFMA-fragment order) + prep (bias-out init, AF build).
// X piece: tid = ((img*1024 + site)*4 + kidx)*64 + l
// AF: AF[((tap*4+kidx)*2+c)*64 + l] = 8 bf16 A-elems (verified layout, RNE).
__global__ __launch_bounds__(256) void k_xform(
    const float* __restrict__ wu, const float* __restrict__ wl,
    uint4v* __restrict__ X,
    const float* __restrict__ kk, uint4v* __restrict__ AF,
    const float* __restrict__ buI, const float* __restrict__ blI,
    float* __restrict__ buO, float* __restrict__ blO)
{
    int tid = blockIdx.x * 256 + threadIdx.x;   // 16384 blocks -> 4Mi pieces

    if (tid < 512 + 4608) {                     // folded prep
        if (tid < 256) buO[tid] = buI[tid];
        else if (tid < 512) blO[tid - 256] = blI[tid - 256];
        else {
            int a    = tid - 512;               // 4608 AF pieces
            int al   = a & 63;
            int c    = (a >> 6) & 1;
            int kidx = (a >> 7) & 3;
            int tap  = a >> 9;                  // 0..8
            const float* kp = kk + ((size_t)tap * 64 + c * 32 + (al & 31)) * 64
                                 + kidx * 16 + (al >> 5) * 8;
            uint4v w;
            #pragma unroll
            for (int pr = 0; pr < 4; pr++)
                w[pr] = f2bf(kp[2 * pr]) | (f2bf(kp[2 * pr + 1]) << 16);   // RNE
            AF[((tap * 4 + kidx) * 2 + c) * 64 + al] = w;
        }
    }

    int l    = tid & 63;
    int kidx = (tid >> 6) & 3;
    int site = (tid >> 8) & 1023;
    int img  = tid >> 18;                       // b*2 + UL
    int b    = img >> 1;
    const float* src = (img & 1) ? wl : wu;
    int o = l & 31, ch = l >> 5;

    const float* p = src + ((size_t)b * 65536 + (size_t)site * 64
                            + kidx * 16 + ch * 8) * 32 + o;
    uint4v w;
    #pragma unroll
    for (int pr = 0; pr < 4; pr++) {
        float g0 = p[(2 * pr) * 32];
        float g1 = p[(2 * pr + 1) * 32];
        w[pr] = __builtin_amdgcn_perm(fbits(g1), fbits(g0), 0x07060302u);
    }
    X[tid] = w;
}

// Pass 2: wave = 2x2 PIXEL TILE (h0..h0+1, w0..w0+1) x 1 ci-half.
// Per row (4 rows): 16 B-fragments feed up to 48 MFMA -> 2.25 MFMA/load
// (1.5x R16). kidx-pair sub-batches keep regs ~150 (cap 170, (256,3)).
// Block = 4 waves (2 w-tiles x 2 ci-halves); 2048 blocks = b x UL x hp x wq.
__global__ __launch_bounds__(256, 3) void k_conv(
    const uint16_t* __restrict__ X, const uint16_t* __restrict__ AF,
    const float* __restrict__ bias,
    float* __restrict__ outU, float* __restrict__ outL,
    float* __restrict__ buO, float* __restrict__ blO)
{
    int tdx  = threadIdx.x;
    int l    = tdx & 63;
    int wid  = tdx >> 6;        // 0..3
    int o    = l & 31;
    int ch   = l >> 5;
    int c    = wid >> 1;        // ci-half owned by this wave
    int wsel = wid & 1;

    int bid = blockIdx.x;       // 2048
    int b   = bid & 7;          // XCD id
    int v   = bid >> 3;         // 0..255
    int hp  = v & 15;           // h-pair
    int wq  = (v >> 4) & 7;     // w-quad
    int UL  = v >> 7;           // 0/1
    int h0  = hp * 2;
    int w0  = wq * 4 + wsel * 2;   // tile's first pixel w
    int img = b * 2 + UL;

    float* dst  = UL ? outL : outU;
    float* bdst = UL ? blO : buO;

    bool sval[4] = { w0 != 0, true, true, w0 + 2 != 32 };
    const char* XB  = (const char*)X;
    const char* AFB = (const char*)AF;

    float bp = 0.f;
    f32x16 acc[2][2];               // [ph][tw]
    #pragma unroll
    for (int ph = 0; ph < 2; ph++)
        #pragma unroll
        for (int tw = 0; tw < 2; tw++) acc[ph][tw] = (f32x16)0.f;

    #pragma unroll
    for (int j = 0; j < 4; j++) {
        int hh = h0 + 2 - j;            // rows h0+2 .. h0-1; pixel ph: r = ph+j-1
        if ((unsigned)hh >= 32u) continue;      // wave-uniform

        const char* ps[4];
        #pragma unroll
        for (int si = 0; si < 4; si++) {
            int ww  = w0 - 1 + si;
            int wwc = ((unsigned)ww < 32u) ? ww : 0;
            ps[si] = XB + ((size_t)(img * 1024 + hh * 32 + wwc)) * 4096
                        + (size_t)l * 16;
        }

        #pragma unroll
        for (int kp2 = 0; kp2 < 2; kp2++) {
            uint4v bw[4][2];
            #pragma unroll
            for (int si = 0; si < 4; si++) {
                if (sval[si]) {
                    #pragma unroll
                    for (int kj = 0; kj < 2; kj++)
                        bw[si][kj] = *(const uint4v*)(ps[si] + (2 * kp2 + kj) * 1024);
                } else {
                    bw[si][0] = (uint4v)0u;
                    bw[si][1] = (uint4v)0u;
                }
            }

            #pragma unroll
            for (int kj = 0; kj < 2; kj++) {
                int kidx = 2 * kp2 + kj;

                // bias: pixel ph = 2-j's own row (hh == h0+ph), own sites tw+1
                if ((j == 1 || j == 2) && c == 0) {
                    float4 b0 = *(const float4*)(bias + kidx * 16 + ch * 8);
                    float4 b1 = *(const float4*)(bias + kidx * 16 + ch * 8 + 4);
                    float bb[8] = {b0.x, b0.y, b0.z, b0.w, b1.x, b1.y, b1.z, b1.w};
                    #pragma unroll
                    for (int pr = 0; pr < 4; pr++) {
                        bp = fmaf(bflo(bw[1][kj][pr]), bb[2 * pr],
                             fmaf(bfhi(bw[1][kj][pr]), bb[2 * pr + 1], bp));
                        bp = fmaf(bflo(bw[2][kj][pr]), bb[2 * pr],
                             fmaf(bfhi(bw[2][kj][pr]), bb[2 * pr + 1], bp));
                    }
                }

                #pragma unroll
                for (int ph = 0; ph < 2; ph++) {
                    int r = ph + j - 1;             // compile-time under unroll
                    if (r >= 0 && r <= 2) {
                        short8 A[3];
                        #pragma unroll
                        for (int kw = 0; kw < 3; kw++)
                            A[kw] = *(const short8*)(AFB
                                    + (size_t)((((r * 3 + kw) * 4 + kidx) * 2 + c) * 64 + l) * 16);
                        #pragma unroll
                        for (int si = 0; si < 4; si++) {
                            short8 Bf = __builtin_bit_cast(short8, bw[si][kj]);
                            #pragma unroll
                            for (int tw = 0; tw < 2; tw++) {
                                int kw = tw + 2 - si;   // compile-time under unroll
                                if (kw >= 0 && kw <= 2)
                                    acc[ph][tw] = __builtin_amdgcn_mfma_f32_32x32x16_bf16(
                                        A[kw], Bf, acc[ph][tw], 0, 0, 0);
                            }
                        }
                    }
                }
            }
        }
    }

    // bias reduction: lanes l, l^32 share o; c==0 wave only
    bp += __shfl_xor(bp, 32);
    if (l < 32 && c == 0) atomicAdd(&bdst[b * 32 + o], bp);

    // stores: col = o (coalesced), row = (reg&3)+8*(reg>>2)+4*(lane>>5)
    #pragma unroll
    for (int ph = 0; ph < 2; ph++) {
        #pragma unroll
        for (int tw = 0; tw < 2; tw++) {
            int h = h0 + ph, w = w0 + tw;
            float* base = dst + ((size_t)b * 65536 + (size_t)(h * 32 + w) * 64 + c * 32) * 32;
            #pragma unroll
            for (int reg = 0; reg < 16; reg++) {
                int row = (reg & 3) + 8 * (reg >> 2) + 4 * (l >> 5);
                base[row * 32 + o] = acc[ph][tw][reg];
            }
        }
    }
}

extern "C" void kernel_launch(void* const* d_in, const int* in_sizes, int n_in,
                              void* d_out, int out_size, void* d_ws, size_t ws_size,
                              hipStream_t stream) {
    const float* wu   = (const float*)d_in[1];
    const float* buI  = (const float*)d_in[2];
    const float* wl   = (const float*)d_in[3];
    const float* blI  = (const float*)d_in[4];
    const float* kk   = (const float*)d_in[5];
    const float* bias = (const float*)d_in[6];

    float* out  = (float*)d_out;
    float* outU = out;
    float* buO  = out + 16777216;
    float* outL = out + 16777216 + 256;
    float* blO  = out + 2 * 16777216 + 256;

    uint4v* AF = (uint4v*)d_ws;                            // 73728 B
    const size_t XOFF = 131072;                            // 128 KiB aligned
    uint4v* X = (uint4v*)((char*)d_ws + XOFF);             // 64 MiB

    k_xform<<<16384, 256, 0, stream>>>(wu, wl, X, kk, AF, buI, blI, buO, blO);
    k_conv<<<2048, 256, 0, stream>>>((const uint16_t*)X, (const uint16_t*)AF, bias,
                                     outU, outL, buO, blO);
}

// Round 19
// 103.252 us; speedup vs baseline: 1.0339x; 1.0181x over previous
//
#include <hip/hip_runtime.h>
#include <cstdint>

typedef __attribute__((ext_vector_type(8))) short short8;
typedef __attribute__((ext_vector_type(16))) float f32x16;
typedef __attribute__((ext_vector_type(4))) unsigned int uint4v;

__device__ inline uint32_t f2bf(float f) {
    union { float f; uint32_t u; } x; x.f = f;
    return (x.u + 0x7FFF + ((x.u >> 16) & 1)) >> 16;
}
__device__ inline uint32_t fbits(float f) {
    union { float f; uint32_t u; } x; x.f = f;
    return x.u;
}
__device__ inline float bflo(uint32_t u) {
    union { uint32_t u; float f; } x; x.u = u << 16; return x.f;
}
__device__ inline float bfhi(uint32_t u) {
    union { uint32_t u; float f; } x; x.u = u & 0xFFFF0000u; return x.f;
}

// Pass 1: X (bf16, MFMA-fragment order) + prep (bias-out init, AF build).
// X piece: tid = ((img*1024 + site)*4 + kidx)*64 + l
// AF: AF[((tap*4+kidx)*2+c)*64 + l] = 8 bf16 A-elems (verified layout, RNE).
__global__ __launch_bounds__(256) void k_xform(
    const float* __restrict__ wu, const float* __restrict__ wl,
    uint4v* __restrict__ X,
    const float* __restrict__ kk, uint4v* __restrict__ AF,
    const float* __restrict__ buI, const float* __restrict__ blI,
    float* __restrict__ buO, float* __restrict__ blO)
{
    int tid = blockIdx.x * 256 + threadIdx.x;   // 16384 blocks -> 4Mi pieces

    if (tid < 512 + 4608) {                     // folded prep
        if (tid < 256) buO[tid] = buI[tid];
        else if (tid < 512) blO[tid - 256] = blI[tid - 256];
        else {
            int a    = tid - 512;               // 4608 AF pieces
            int al   = a & 63;
            int c    = (a >> 6) & 1;
            int kidx = (a >> 7) & 3;
            int tap  = a >> 9;                  // 0..8
            const float* kp = kk + ((size_t)tap * 64 + c * 32 + (al & 31)) * 64
                                 + kidx * 16 + (al >> 5) * 8;
            uint4v w;
            #pragma unroll
            for (int pr = 0; pr < 4; pr++)
                w[pr] = f2bf(kp[2 * pr]) | (f2bf(kp[2 * pr + 1]) << 16);   // RNE
            AF[((tap * 4 + kidx) * 2 + c) * 64 + al] = w;
        }
    }

    int l    = tid & 63;
    int kidx = (tid >> 6) & 3;
    int site = (tid >> 8) & 1023;
    int img  = tid >> 18;                       // b*2 + UL
    int b    = img >> 1;
    const float* src = (img & 1) ? wl : wu;
    int o = l & 31, ch = l >> 5;

    const float* p = src + ((size_t)b * 65536 + (size_t)site * 64
                            + kidx * 16 + ch * 8) * 32 + o;
    uint4v w;
    #pragma unroll
    for (int pr = 0; pr < 4; pr++) {
        float g0 = p[(2 * pr) * 32];
        float g1 = p[(2 * pr + 1) * 32];
        w[pr] = __builtin_amdgcn_perm(fbits(g1), fbits(g0), 0x07060302u);
    }
    X[tid] = w;
}

// Pass 2: wave = 2 pixels x 1 ci-half (acc 32). Full 16-fragment B-batch per
// row, with sched_barrier(0) fencing the load cluster from the consume cluster
// so the compiler cannot re-serialize the batch (deep vmcnt pipeline).
// Block = 4 waves (2 w-pairs x 2 ci-halves); UL serialized (XCD X set = 1 img).
__global__ __launch_bounds__(256, 3) void k_conv(
    const uint16_t* __restrict__ X, const uint16_t* __restrict__ AF,
    const float* __restrict__ bias,
    float* __restrict__ outU, float* __restrict__ outL,
    float* __restrict__ buO, float* __restrict__ blO)
{
    int tdx  = threadIdx.x;
    int l    = tdx & 63;
    int wid  = tdx >> 6;        // 0..3
    int o    = l & 31;
    int ch   = l >> 5;
    int c    = wid >> 1;        // ci-half owned by this wave
    int wsel = wid & 1;

    int bid = blockIdx.x;       // 2048
    int b   = bid & 7;          // XCD id
    int v   = bid >> 3;         // 0..255
    int h   = v & 31;
    int wq  = v >> 5;           // 0..7
    int w0  = wq * 4 + wsel * 2;   // wave's first pixel w

    bool sval[4] = { w0 != 0, true, true, w0 + 2 != 32 };
    const char* XB  = (const char*)X;
    const char* AFB = (const char*)AF;

    for (int UL = 0; UL < 2; UL++) {
        int img = b * 2 + UL;
        float* dst  = UL ? outL : outU;
        float* bdst = UL ? blO : buO;

        float bp = 0.f;
        f32x16 acc[2];              // [tw]
        acc[0] = (f32x16)0.f;
        acc[1] = (f32x16)0.f;

        for (int r = 0; r < 3; r++) {
            int hh = h + 1 - r;
            if ((unsigned)hh >= 32u) continue;      // wave-uniform

            // ---- batch ALL 16 B-fragment loads (4 sites x 4 kidx, 1KB each) ----
            uint4v bw[4][4];
            #pragma unroll
            for (int si = 0; si < 4; si++) {
                int ww  = w0 - 1 + si;
                int wwc = ((unsigned)ww < 32u) ? ww : 0;
                const char* ps = XB + ((size_t)(img * 1024 + hh * 32 + wwc)) * 4096
                                    + (size_t)l * 16;
                if (sval[si]) {
                    #pragma unroll
                    for (int kidx = 0; kidx < 4; kidx++)
                        bw[si][kidx] = *(const uint4v*)(ps + kidx * 1024);
                } else {
                    #pragma unroll
                    for (int kidx = 0; kidx < 4; kidx++) bw[si][kidx] = (uint4v)0u;
                }
            }
            // fence: forbid sinking the loads into the MFMA stream -> 16-deep vmcnt
            __builtin_amdgcn_sched_barrier(0);

            // ---- consume per kidx: 3 A-frags (this c), bias, 6 MFMA ----
            #pragma unroll
            for (int kidx = 0; kidx < 4; kidx++) {
                short8 A[3];
                #pragma unroll
                for (int kw = 0; kw < 3; kw++)
                    A[kw] = *(const short8*)(AFB
                            + (size_t)((((r * 3 + kw) * 4 + kidx) * 2 + c) * 64 + l) * 16);

                if (r == 1 && c == 0) {     // bias: own pixels (sites 1,2), c0 wave only
                    float4 b0 = *(const float4*)(bias + kidx * 16 + ch * 8);
                    float4 b1 = *(const float4*)(bias + kidx * 16 + ch * 8 + 4);
                    float bb[8] = {b0.x, b0.y, b0.z, b0.w, b1.x, b1.y, b1.z, b1.w};
                    #pragma unroll
                    for (int pr = 0; pr < 4; pr++) {
                        bp = fmaf(bflo(bw[1][kidx][pr]), bb[2 * pr],
                             fmaf(bfhi(bw[1][kidx][pr]), bb[2 * pr + 1], bp));
                        bp = fmaf(bflo(bw[2][kidx][pr]), bb[2 * pr],
                             fmaf(bfhi(bw[2][kidx][pr]), bb[2 * pr + 1], bp));
                    }
                }

                #pragma unroll
                for (int si = 0; si < 4; si++) {
                    short8 Bf = __builtin_bit_cast(short8, bw[si][kidx]);
                    #pragma unroll
                    for (int tw = 0; tw < 2; tw++) {
                        int kw = tw + 2 - si;           // compile-time under unroll
                        if (kw >= 0 && kw <= 2)
                            acc[tw] = __builtin_amdgcn_mfma_f32_32x32x16_bf16(
                                A[kw], Bf, acc[tw], 0, 0, 0);
                    }
                }
            }
        }

        // bias reduction: lanes l, l^32 share o; one wave per pixel-pair (c==0)
        bp += __shfl_xor(bp, 32);
        if (l < 32 && c == 0) atomicAdd(&bdst[b * 32 + o], bp);

        // stores: col = o (coalesced), row = (reg&3)+8*(reg>>2)+4*(lane>>5)
        #pragma unroll
        for (int tw = 0; tw < 2; tw++) {
            int w = w0 + tw;
            float* base = dst + ((size_t)b * 65536 + (size_t)(h * 32 + w) * 64 + c * 32) * 32;
            #pragma unroll
            for (int reg = 0; reg < 16; reg++) {
                int row = (reg & 3) + 8 * (reg >> 2) + 4 * (l >> 5);
                base[row * 32 + o] = acc[tw][reg];
            }
        }
    }
}

extern "C" void kernel_launch(void* const* d_in, const int* in_sizes, int n_in,
                              void* d_out, int out_size, void* d_ws, size_t ws_size,
                              hipStream_t stream) {
    const float* wu   = (const float*)d_in[1];
    const float* buI  = (const float*)d_in[2];
    const float* wl   = (const float*)d_in[3];
    const float* blI  = (const float*)d_in[4];
    const float* kk   = (const float*)d_in[5];
    const float* bias = (const float*)d_in[6];

    float* out  = (float*)d_out;
    float* outU = out;
    float* buO  = out + 16777216;
    float* outL = out + 16777216 + 256;
    float* blO  = out + 2 * 16777216 + 256;

    uint4v* AF = (uint4v*)d_ws;                            // 73728 B
    const size_t XOFF = 131072;                            // 128 KiB aligned
    uint4v* X = (uint4v*)((char*)d_ws + XOFF);             // 64 MiB

    k_xform<<<16384, 256, 0, stream>>>(wu, wl, X, kk, AF, buI, blI, buO, blO);
    k_conv<<<2048, 256, 0, stream>>>((const uint16_t*)X, (const uint16_t*)AF, bias,
                                     outU, outL, buO, blO);
}

// Round 20
// 102.441 us; speedup vs baseline: 1.0421x; 1.0079x over previous
//
#include <hip/hip_runtime.h>
#include <cstdint>

typedef __attribute__((ext_vector_type(8))) short short8;
typedef __attribute__((ext_vector_type(16))) float f32x16;
typedef __attribute__((ext_vector_type(4))) unsigned int uint4v;

__device__ inline uint32_t f2bf(float f) {
    union { float f; uint32_t u; } x; x.f = f;
    return (x.u + 0x7FFF + ((x.u >> 16) & 1)) >> 16;
}
__device__ inline uint32_t fbits(float f) {
    union { float f; uint32_t u; } x; x.f = f;
    return x.u;
}
__device__ inline float bflo(uint32_t u) {
    union { uint32_t u; float f; } x; x.u = u << 16; return x.f;
}
__device__ inline float bfhi(uint32_t u) {
    union { uint32_t u; float f; } x; x.u = u & 0xFFFF0000u; return x.f;
}

// async 16B/lane global->LDS DMA: lds dest = uniform base + lane*16.
__device__ inline void dma16(const void* g, void* lds) {
    __builtin_amdgcn_global_load_lds(
        (const __attribute__((address_space(1))) unsigned int*)g,
        (__attribute__((address_space(3))) unsigned int*)lds, 16, 0, 0);
}

// Pass 1: X (bf16, MFMA-fragment order) + prep (bias-out init, AF build).
// X piece: tid = ((img*1024 + site)*4 + kidx)*64 + l
// AF: AF[((tap*4+kidx)*2+c)*64 + l] = 8 bf16 A-elems (verified layout, RNE).
__global__ __launch_bounds__(256) void k_xform(
    const float* __restrict__ wu, const float* __restrict__ wl,
    uint4v* __restrict__ X,
    const float* __restrict__ kk, uint4v* __restrict__ AF,
    const float* __restrict__ buI, const float* __restrict__ blI,
    float* __restrict__ buO, float* __restrict__ blO)
{
    int tid = blockIdx.x * 256 + threadIdx.x;   // 16384 blocks -> 4Mi pieces

    if (tid < 512 + 4608) {                     // folded prep
        if (tid < 256) buO[tid] = buI[tid];
        else if (tid < 512) blO[tid - 256] = blI[tid - 256];
        else {
            int a    = tid - 512;               // 4608 AF pieces
            int al   = a & 63;
            int c    = (a >> 6) & 1;
            int kidx = (a >> 7) & 3;
            int tap  = a >> 9;                  // 0..8
            const float* kp = kk + ((size_t)tap * 64 + c * 32 + (al & 31)) * 64
                                 + kidx * 16 + (al >> 5) * 8;
            uint4v w;
            #pragma unroll
            for (int pr = 0; pr < 4; pr++)
                w[pr] = f2bf(kp[2 * pr]) | (f2bf(kp[2 * pr + 1]) << 16);   // RNE
            AF[((tap * 4 + kidx) * 2 + c) * 64 + al] = w;
        }
    }

    int l    = tid & 63;
    int kidx = (tid >> 6) & 3;
    int site = (tid >> 8) & 1023;
    int img  = tid >> 18;                       // b*2 + UL
    int b    = img >> 1;
    const float* src = (img & 1) ? wl : wu;
    int o = l & 31, ch = l >> 5;

    const float* p = src + ((size_t)b * 65536 + (size_t)site * 64
                            + kidx * 16 + ch * 8) * 32 + o;
    uint4v w;
    #pragma unroll
    for (int pr = 0; pr < 4; pr++) {
        float g0 = p[(2 * pr) * 32];
        float g1 = p[(2 * pr + 1) * 32];
        w[pr] = __builtin_amdgcn_perm(fbits(g1), fbits(g0), 0x07060302u);
    }
    X[tid] = w;
}

// Pass 2: DMA-staged double-buffered LDS (m97/T3 recipe).
// Block = 4 waves (2 w-pairs x 2 ci-halves) sharing 6 sites/row.
// tiles[2][6][4][512] = 49152 B -> 3 blocks/CU. Per UL:
//   STAGE(buf0,r0); bar; { STAGE(buf^1,r+1); COMPUTE(buf,r); bar; }*
// DMA depth is queue-held (no VGPR batch for the compiler to re-serialize).
__global__ __launch_bounds__(256, 3) void k_conv(
    const uint16_t* __restrict__ X, const uint16_t* __restrict__ AF,
    const float* __restrict__ bias,
    float* __restrict__ outU, float* __restrict__ outL,
    float* __restrict__ buO, float* __restrict__ blO)
{
    __shared__ uint16_t tiles[2][6][4][512];    // 49152 B

    int tdx  = threadIdx.x;
    int l    = tdx & 63;
    int wid  = tdx >> 6;        // 0..3
    int o    = l & 31;
    int ch   = l >> 5;
    int c    = wid >> 1;        // ci-half owned by this wave
    int wsel = wid & 1;

    int bid = blockIdx.x;       // 2048
    int b   = bid & 7;          // XCD id
    int v   = bid >> 3;         // 0..255
    int h   = v & 31;
    int wq  = v >> 5;           // 0..7
    int w0  = wq * 4 + wsel * 2;   // wave's first pixel w

    int rstart = (h == 31) ? 1 : 0;
    int nr     = (h == 0 || h == 31) ? 2 : 3;

    const char* XB  = (const char*)X;
    const char* AFB = (const char*)AF;

    for (int UL = 0; UL < 2; UL++) {
        int img = b * 2 + UL;
        float* dst  = UL ? outL : outU;
        float* bdst = UL ? blO : buO;

        float bp = 0.f;
        f32x16 acc[2];              // [tw]
        acc[0] = (f32x16)0.f;
        acc[1] = (f32x16)0.f;

        // ---- STAGE(bf, r): this wave DMA-stages pieces wid*6 .. wid*6+5 ----
        auto STAGE = [&](int bf, int r) {
            int hh = h + 1 - r;                     // valid by construction
            #pragma unroll
            for (int i = 0; i < 6; i++) {
                int p = wid * 6 + i;
                int s = p >> 2, k = p & 3;          // slot 0..5, kidx 0..3
                int ww = wq * 4 - 1 + s;            // wave-uniform
                void* ldst = (void*)&tiles[bf][s][k][0];
                if ((unsigned)ww < 32u) {
                    const char* g = XB + ((size_t)(img * 1024 + hh * 32 + ww)) * 4096
                                       + (size_t)k * 1024 + (size_t)l * 16;
                    dma16(g, ldst);
                } else {
                    *(uint4v*)((char*)ldst + l * 16) = (uint4v)0u;
                }
            }
        };

        // ---- COMPUTE(bf, r): ds_read fragments + A + bias + 24 MFMA ----
        auto COMPUTE = [&](int bf, int r) {
            #pragma unroll
            for (int kidx = 0; kidx < 4; kidx++) {
                short8 A[3];
                #pragma unroll
                for (int kw = 0; kw < 3; kw++)
                    A[kw] = *(const short8*)(AFB
                            + (size_t)((((r * 3 + kw) * 4 + kidx) * 2 + c) * 64 + l) * 16);

                uint4v bw[4];
                #pragma unroll
                for (int si = 0; si < 4; si++) {
                    int s = 2 * wsel + si;          // slot for this wave's site si
                    bw[si] = *(const uint4v*)((const char*)&tiles[bf][s][kidx][0] + l * 16);
                }

                if (r == 1 && c == 0) {     // bias: own pixels (sites 1,2), c0 wave
                    float4 b0 = *(const float4*)(bias + kidx * 16 + ch * 8);
                    float4 b1 = *(const float4*)(bias + kidx * 16 + ch * 8 + 4);
                    float bb[8] = {b0.x, b0.y, b0.z, b0.w, b1.x, b1.y, b1.z, b1.w};
                    #pragma unroll
                    for (int pr = 0; pr < 4; pr++) {
                        bp = fmaf(bflo(bw[1][pr]), bb[2 * pr],
                             fmaf(bfhi(bw[1][pr]), bb[2 * pr + 1], bp));
                        bp = fmaf(bflo(bw[2][pr]), bb[2 * pr],
                             fmaf(bfhi(bw[2][pr]), bb[2 * pr + 1], bp));
                    }
                }

                #pragma unroll
                for (int si = 0; si < 4; si++) {
                    short8 Bf = __builtin_bit_cast(short8, bw[si]);
                    #pragma unroll
                    for (int tw = 0; tw < 2; tw++) {
                        int kw = tw + 2 - si;       // compile-time under unroll
                        if (kw >= 0 && kw <= 2)
                            acc[tw] = __builtin_amdgcn_mfma_f32_32x32x16_bf16(
                                A[kw], Bf, acc[tw], 0, 0, 0);
                    }
                }
            }
        };

        // ---- T3 2-phase pipeline (one barrier per row) ----
        STAGE(0, rstart);
        __syncthreads();                // DMA drained (vmcnt0 at barrier)
        for (int i = 0; i < nr; i++) {
            int r = rstart + i;
            if (i + 1 < nr) STAGE((i + 1) & 1, r + 1);   // DMA into other buffer
            COMPUTE(i & 1, r);                           // overlaps DMA flight
            __syncthreads();                             // next buf ready; readers done
        }

        // bias reduction: lanes l, l^32 share o; c==0 wave only
        bp += __shfl_xor(bp, 32);
        if (l < 32 && c == 0) atomicAdd(&bdst[b * 32 + o], bp);

        // stores: col = o (coalesced), row = (reg&3)+8*(reg>>2)+4*(lane>>5)
        #pragma unroll
        for (int tw = 0; tw < 2; tw++) {
            int w = w0 + tw;
            float* base = dst + ((size_t)b * 65536 + (size_t)(h * 32 + w) * 64 + c * 32) * 32;
            #pragma unroll
            for (int reg = 0; reg < 16; reg++) {
                int row = (reg & 3) + 8 * (reg >> 2) + 4 * (l >> 5);
                base[row * 32 + o] = acc[tw][reg];
            }
        }
    }
}

extern "C" void kernel_launch(void* const* d_in, const int* in_sizes, int n_in,
                              void* d_out, int out_size, void* d_ws, size_t ws_size,
                              hipStream_t stream) {
    const float* wu   = (const float*)d_in[1];
    const float* buI  = (const float*)d_in[2];
    const float* wl   = (const float*)d_in[3];
    const float* blI  = (const float*)d_in[4];
    const float* kk   = (const float*)d_in[5];
    const float* bias = (const float*)d_in[6];

    float* out  = (float*)d_out;
    float* outU = out;
    float* buO  = out + 16777216;
    float* outL = out + 16777216 + 256;
    float* blO  = out + 2 * 16777216 + 256;

    uint4v* AF = (uint4v*)d_ws;                            // 73728 B
    const size_t XOFF = 131072;                            // 128 KiB aligned
    uint4v* X = (uint4v*)((char*)d_ws + XOFF);             // 64 MiB

    k_xform<<<16384, 256, 0, stream>>>(wu, wl, X, kk, AF, buI, blI, buO, blO);
    k_conv<<<2048, 256, 0, stream>>>((const uint16_t*)X, (const uint16_t*)AF, bias,
                                     outU, outL, buO, blO);
}